// Round 1
// 238.878 us; speedup vs baseline: 1.0048x; 1.0048x over previous
//
#include <hip/hip_runtime.h>

#define BATCH_L 524288
#define NL 40
#define NXL 20
#define BLOCK 256
#define GRID 2048
#define NTHREADS (GRID * BLOCK)              // 524288
#define NCHUNK (BATCH_L * 10)                // 5,242,880 float4 chunks per array
#define CITERS (NCHUNK / NTHREADS)           // 10 chunks per thread

// R5: chunk-ownership rewrite. Each thread owns ONE float4 chunk (4 columns)
// per iteration, consecutive lanes own consecutive chunks -> every pred/targ/
// ycur load is a perfectly coalesced wave64 dwordx4 (8 cache lines/instr vs
// ~40 for the old 80B-strided half-row layout; TA line-accesses drop 3x).
// Stencil halo = 3 floats per chunk: an aligned float2 at col q-2 (q even)
// and a dword at col q+4, periodic wrap only at cr==0 / cr==9. Halo loads are
// L1 hits (same lines as neighbor lanes' dwordx4). dd term is a global sum so
// it needs no ownership: masked by cr<5. No LDS staging, no barriers, no
// shuffles in the stream.
__global__ void hybrid_loss_main(
    const float4* __restrict__ pred4,
    const float4* __restrict__ targ4,
    const float4* __restrict__ ycur4,
    double* __restrict__ partials)     // [GRID][2]
{
    const int t = blockIdx.x * BLOCK + threadIdx.x;
    const float*  __restrict__ predf = reinterpret_cast<const float*>(pred4);
    const float2* __restrict__ pred2 = reinterpret_cast<const float2*>(pred4);

    double sdd = 0.0, spi = 0.0;

#pragma unroll 2
    for (int it = 0; it < CITERS; ++it) {
        const unsigned chunk = (unsigned)t + (unsigned)it * (unsigned)NTHREADS;
        const unsigned row   = chunk / 10u;          // magic-mul, per-iter independent
        const int      cr    = (int)(chunk - row * 10u);
        const int      c4    = cr * 4;               // first column of this chunk
        const unsigned rbase = row * (unsigned)NL;   // first float of this row

        // Periodic halo addresses (wrap only at the row edges).
        const int im2 = (cr == 0) ? 38 : (c4 - 2);   // col of p[q-2] (even -> f2 aligned)
        const int ip1 = (cr == 9) ? 0  : (c4 + 4);   // col of p[q+4]

        // 5 loads, all contiguous across lanes (dwordx4/dwordx2/dword).
        const float4 P = pred4[chunk];
        const float4 T = targ4[chunk];
        const float4 Y = ycur4[chunk];
        const float2 M = pred2[(rbase + (unsigned)im2) >> 1];  // {p[q-2], p[q-1]}
        const float  R = predf[rbase + (unsigned)ip1];         // p[q+4]

        // Data-driven MSE: chunk columns are q..q+3, all < 20 iff cr < 5.
        {
            const float d0 = P.x - T.x, d1 = P.y - T.y;
            const float d2 = P.z - T.z, d3 = P.w - T.w;
            const float s = d0 * d0 + d1 * d1 + d2 * d2 + d3 * d3;
            if (cr < 5) sdd += (double)s;
        }

        // Physics term: d_i = (101 p_i - 100 y_i - 8) - (p_{i+1} - p_{i-2}) * p_{i-1}
        {
            const float d0 = (101.f * P.x - 100.f * Y.x - 8.f) - (P.y - M.x) * M.y;
            const float d1 = (101.f * P.y - 100.f * Y.y - 8.f) - (P.z - M.y) * P.x;
            const float d2 = (101.f * P.z - 100.f * Y.z - 8.f) - (P.w - P.x) * P.y;
            const float d3 = (101.f * P.w - 100.f * Y.w - 8.f) - (R   - P.y) * P.z;
            spi += (double)(d0 * d0 + d1 * d1 + d2 * d2 + d3 * d3);
        }
    }

    // Wave shuffle reduction in double -> LDS -> per-block partial.
#pragma unroll
    for (int off = 32; off > 0; off >>= 1) {
        sdd += __shfl_down(sdd, off, 64);
        spi += __shfl_down(spi, off, 64);
    }
    __shared__ double lds_red[2 * (BLOCK / 64)];
    const int lane = threadIdx.x & 63;
    const int wave = threadIdx.x >> 6;
    if (lane == 0) { lds_red[2 * wave] = sdd; lds_red[2 * wave + 1] = spi; }
    __syncthreads();
    if (threadIdx.x == 0) {
        double tsd = 0.0, tsp = 0.0;
#pragma unroll
        for (int w = 0; w < BLOCK / 64; ++w) {
            tsd += lds_red[2 * w];
            tsp += lds_red[2 * w + 1];
        }
        partials[2 * blockIdx.x]     = tsd;   // every slot written every launch
        partials[2 * blockIdx.x + 1] = tsp;
    }
}

__global__ __launch_bounds__(256) void hybrid_loss_finalize(
    const double* __restrict__ partials, float* __restrict__ out)
{
    const double2* __restrict__ p2 = reinterpret_cast<const double2*>(partials);
    double sd = 0.0, sp = 0.0;
    for (int m = threadIdx.x; m < GRID; m += 256) {
        const double2 v = p2[m];
        sd += v.x; sp += v.y;
    }
#pragma unroll
    for (int off = 32; off > 0; off >>= 1) {
        sd += __shfl_down(sd, off, 64);
        sp += __shfl_down(sp, off, 64);
    }
    __shared__ double lds[8];
    const int lane = threadIdx.x & 63;
    const int wave = threadIdx.x >> 6;
    if (lane == 0) { lds[2 * wave] = sd; lds[2 * wave + 1] = sp; }
    __syncthreads();
    if (threadIdx.x == 0) {
        double tsd = 0.0, tsp = 0.0;
#pragma unroll
        for (int w = 0; w < 4; ++w) { tsd += lds[2 * w]; tsp += lds[2 * w + 1]; }
        const double l_dd = tsd / ((double)BATCH_L * NXL);
        const double l_pi = tsp / ((double)BATCH_L * NL);
        out[0] = (float)(l_dd + 0.1 * l_pi);
        out[1] = (float)l_dd;
        out[2] = (float)l_pi;
    }
}

extern "C" void kernel_launch(void* const* d_in, const int* in_sizes, int n_in,
                              void* d_out, int out_size, void* d_ws, size_t ws_size,
                              hipStream_t stream) {
    const float4* pred = (const float4*)d_in[0];
    const float4* targ = (const float4*)d_in[1];
    const float4* ycur = (const float4*)d_in[2];
    double* partials = (double*)d_ws;          // GRID * 2 doubles = 32 KB
    float* out = (float*)d_out;

    hybrid_loss_main<<<GRID, BLOCK, 0, stream>>>(pred, targ, ycur, partials);
    hybrid_loss_finalize<<<1, 256, 0, stream>>>(partials, out);
}